// Round 13
// baseline (324.871 us; speedup 1.0000x reference)
//
#include <hip/hip_runtime.h>
#include <cstdint>
#include <cstddef>

typedef unsigned int u32;
typedef unsigned short u16;
typedef __bf16 bf16x8 __attribute__((ext_vector_type(8)));
typedef float f32x4 __attribute__((ext_vector_type(4)));
typedef u16 u16x8 __attribute__((ext_vector_type(8)));

static constexpr int T_TOK = 4096;
static constexpr int HID   = 2048;
static constexpr int INTER = 1024;
static constexpr int NEXP  = 8;
static constexpr int TOPK  = 2;
static constexpr int SLOT_CAP = 9216;    // 8192 real + per-expert 128-align pad
static constexpr int NT_M = 72;          // 128-row m-tiles
static constexpr int NT_N = 16;          // 128-col n-tiles (N=2048)

// meta int indices
static constexpr int M_TOT  = 16;
static constexpr int M_CUR  = 17;    // 8 router cursors
static constexpr int M_DONE = 128;   // 72 per-mt done counters
static constexpr int M_TOK  = 256;   // toklist[SLOT_CAP], values t*2+k

__device__ __forceinline__ u16 f2bf(float f) {
  u32 u = __builtin_bit_cast(u32, f);
  u32 r = (u + 0x7fffu + ((u >> 16) & 1u)) >> 16;
  return (u16)r;
}
__device__ __forceinline__ float bf2f(u16 h) {
  return __builtin_bit_cast(float, (u32)h << 16);
}

// RELAXED poll + one acquire fence after success (R11-validated).
__device__ __forceinline__ void spin_ge(int* p, int target) {
  while (__hip_atomic_load(p, __ATOMIC_RELAXED, __HIP_MEMORY_SCOPE_AGENT) < target)
    __builtin_amdgcn_s_sleep(8);
  __builtin_amdgcn_fence(__ATOMIC_ACQUIRE, "agent");
}
// stores done -> __syncthreads() (drains all waves' vmcnt) -> tid0 release RMW.
__device__ __forceinline__ void bump(int* p, int tid) {
  __syncthreads();
  if (tid == 0)
    __hip_atomic_fetch_add(p, 1, __ATOMIC_RELEASE, __HIP_MEMORY_SCOPE_AGENT);
}

// ---------------- router ----------------
__global__ void router_count(const int* __restrict__ eidx, int* __restrict__ meta) {
  __shared__ int cnt[NEXP];
  const int tid = threadIdx.x;
  if (tid < NEXP) cnt[tid] = 0;
  __syncthreads();
  for (int i = tid; i < T_TOK * TOPK; i += 256) atomicAdd(&cnt[eidx[i]], 1);
  __syncthreads();
  if (tid == 0) {
    int off = 0;
    for (int e = 0; e < NEXP; ++e) {
      int c = cnt[e];
      meta[e] = c;
      meta[8 + e] = off;
      meta[M_CUR + e] = off;
      off += (c + 127) & ~127;      // 128-aligned regions (BM=128)
    }
    meta[M_TOT] = off;
  }
}

__global__ void init_k(int* __restrict__ meta) {
  const int i = blockIdx.x * 256 + threadIdx.x;
  if (i < SLOT_CAP) meta[M_TOK + i] = 0;     // pad rows gather token 0 (writes skipped)
  if (i >= M_DONE && i < M_DONE + NT_M) meta[i] = 0;
}

__global__ void router_assign(const int* __restrict__ eidx, int* __restrict__ meta) {
  const int t = blockIdx.x * 256 + threadIdx.x;
  if (t >= T_TOK) return;
  int* cursors = meta + M_CUR;
  int* toklist = meta + M_TOK;
  for (int k = 0; k < TOPK; ++k) {
    const int e = eidx[t * TOPK + k];
    const int pos = atomicAdd(&cursors[e], 1);
    toklist[pos] = t * 2 + k;
  }
}

// ---------------- dequant helper (1 thread = 4 int32 -> 8 bf16) ----------------
template <int CPR>
__device__ __forceinline__ void deq1(const int* __restrict__ p, const float* __restrict__ s,
                                     u16* __restrict__ w, int gid) {
  const int row = gid / CPR;
  const int cid = gid % CPR;
  const int4 pk = *(const int4*)(p + (size_t)gid * 4);
  const float sc = s[(size_t)row * (CPR / 4) + (cid >> 2)];
  int v[4] = {pk.x, pk.y, pk.z, pk.w};
  u16x8 o;
#pragma unroll
  for (int b = 0; b < 4; ++b) {
    o[2 * b]     = f2bf((float)((v[b] & 15) - 8) * sc);
    o[2 * b + 1] = f2bf((float)(((v[b] >> 4) & 15) - 8) * sc);
  }
  *(u16x8*)(w + (size_t)gid * 8) = o;
}

// ---------------- merged prep: [0,16384) deqW1, [16384,24576) deqW2, [24576,28672) cast ----------------
__global__ void prep_k(const int* __restrict__ w1, const float* __restrict__ w1s,
                       const int* __restrict__ w2, const float* __restrict__ w2s,
                       const float* __restrict__ x, u16* __restrict__ W1b,
                       u16* __restrict__ W2b, u16* __restrict__ xb) {
  const int blk = blockIdx.x;
  if (blk < 16384) {
    deq1<256>(w1, w1s, W1b, blk * 256 + threadIdx.x);
  } else if (blk < 24576) {
    deq1<128>(w2, w2s, W2b, (blk - 16384) * 256 + threadIdx.x);
  } else {
    const int i = ((blk - 24576) * 256 + threadIdx.x) * 8;
    const float4 a = *(const float4*)(x + i);
    const float4 b = *(const float4*)(x + i + 4);
    u16x8 o;
    o[0] = f2bf(a.x); o[1] = f2bf(a.y); o[2] = f2bf(a.z); o[3] = f2bf(a.w);
    o[4] = f2bf(b.x); o[5] = f2bf(b.y); o[6] = f2bf(b.z); o[7] = f2bf(b.w);
    *(u16x8*)(xb + i) = o;
  }
}

// ---------------- 128x128 GEMM tile body (m97 2-barrier loop + conflict-free swizzle) ----------------
// C[slot, n] = sum_k A[row(slot), k] * B[n, k]  (B K-major). BM=BN=128, BK=64,
// 4 waves (2M x 2N), wave tile 64x64, single-buffer LDS 32KB (A 16K + B 16K).
// R12 post-mortem: 256^2 1-block/CU had schedule-invariant ~22% MfmaUtil (no
// co-resident block to mask barrier/vmcnt stalls, m114). 128^2 at 32KB LDS ->
// ~3 blocks/CU co-resident at different phases = cross-block masking (m97's
// actual mechanism). Swizzle o^=((o>>7)&3)<<4 (PMC-verified conflict-free).
// G1M: gather A rows via toklist>>1, fused silu(gate)*up epilogue (64 h-cols).
// !G1M: token-scatter epilogue into yt[toklist[slot]] (pads skipped via vend).
template <int KT, bool G1M>
__device__ void tile128(const u16* __restrict__ A, const u16* __restrict__ Be,
                        u16* __restrict__ Cout, const int* __restrict__ toklist,
                        int vend, u16* lds, int slot0, int nt, int tid) {
  static constexpr int NT = KT / 64;
  char* ldsB = (char*)lds;

  const u16* asrc[4];
  const u16* bsrc[4];
#pragma unroll
  for (int j = 0; j < 4; ++j) {
    const int L = j * 4096 + tid * 16;
    const int S = L >> 10;
    int o = L & 1023;
    o ^= ((o >> 7) & 3) << 4;
    const int r = (S >> 1) * 16 + (o >> 6);     // tile row 0..127
    const int cb = (S & 1) * 64 + (o & 63);     // col byte 0..127
    const int arow = G1M ? (toklist[slot0 + r] >> 1) : (slot0 + r);
    asrc[j] = A + (size_t)arow * KT + (cb >> 1);
    int brow;
    if (G1M) {
      const int w = r >> 6, j6 = r & 63;        // gate rows j6<32, up rows j6>=32
      brow = (j6 < 32) ? (nt * 64 + w * 32 + j6)
                       : (1024 + nt * 64 + w * 32 + (j6 & 31));
    } else {
      brow = nt * 128 + r;
    }
    bsrc[j] = Be + (size_t)brow * KT + (cb >> 1);
  }

  const int lane = tid & 63;
  const int wid = tid >> 6;          // 0..3
  const int wm = (wid >> 1) * 64;
  const int wn = (wid & 1) * 64;
  const int fr = lane & 15;
  const int qq = lane >> 4;
  const int swz = (qq * 16) ^ (((fr >> 1) & 3) << 4);

  const int abase = (wm >> 4) * 2048 + fr * 64 + swz;            // + m*2048 + ks*1024
  const int bbase = 16384 + (wn >> 4) * 2048 + fr * 64 + swz;    // + n*2048 + ks*1024

  f32x4 acc[4][4];
#pragma unroll
  for (int m = 0; m < 4; ++m)
#pragma unroll
    for (int n = 0; n < 4; ++n) acc[m][n] = (f32x4)0.0f;

#pragma unroll 1
  for (int kt = 0; kt < NT; ++kt) {
    __syncthreads();
#pragma unroll
    for (int j = 0; j < 4; ++j) {
      __builtin_amdgcn_global_load_lds(
          (const __attribute__((address_space(1))) void*)(asrc[j] + kt * 64),
          (__attribute__((address_space(3))) void*)(ldsB + j * 4096 + tid * 16),
          16, 0, 0);
      __builtin_amdgcn_global_load_lds(
          (const __attribute__((address_space(1))) void*)(bsrc[j] + kt * 64),
          (__attribute__((address_space(3))) void*)(ldsB + 16384 + j * 4096 + tid * 16),
          16, 0, 0);
    }
    __syncthreads();
#pragma unroll
    for (int ks = 0; ks < 2; ++ks) {
      bf16x8 a[4], b[4];
#pragma unroll
      for (int m = 0; m < 4; ++m)
        a[m] = *(const bf16x8*)(ldsB + abase + m * 2048 + ks * 1024);
#pragma unroll
      for (int n = 0; n < 4; ++n)
        b[n] = *(const bf16x8*)(ldsB + bbase + n * 2048 + ks * 1024);
#pragma unroll
      for (int m = 0; m < 4; ++m)
#pragma unroll
        for (int n = 0; n < 4; ++n)
          acc[m][n] = __builtin_amdgcn_mfma_f32_16x16x32_bf16(a[m], b[n], acc[m][n], 0, 0, 0);
    }
  }

  // epilogue: C/D layout col=lane&15, row=(lane>>4)*4+j  [m89-verified]
  if (G1M) {
    const int g = wid & 1;
#pragma unroll
    for (int m = 0; m < 4; ++m)
#pragma unroll
      for (int n = 0; n < 2; ++n)
#pragma unroll
        for (int jj = 0; jj < 4; ++jj) {
          const float gv = acc[m][n][jj];
          const float uv = acc[m][n + 2][jj];
          const float hv = gv / (1.0f + __expf(-gv)) * uv;
          const int row = slot0 + wm + m * 16 + qq * 4 + jj;
          Cout[(size_t)row * INTER + nt * 64 + g * 32 + n * 16 + fr] = f2bf(hv);
        }
  } else {
#pragma unroll
    for (int m = 0; m < 4; ++m)
#pragma unroll
      for (int jj = 0; jj < 4; ++jj) {
        const int slot = slot0 + wm + m * 16 + qq * 4 + jj;
        if (slot < vend) {
          const int tk = toklist[slot];
          const int col = nt * 128 + wn + fr;
#pragma unroll
          for (int n = 0; n < 4; ++n)
            Cout[(size_t)tk * HID + col + n * 16] = f2bf(acc[m][n][jj]);
        }
      }
  }
}

// ---------------- fused GEMM kernel: 1152 blocks, block j = (mt=j>>4, nt=j&15) ----------------
// Each block: G1 tile (mt,nt) -> bump done[mt] -> spin done[mt]==16 (siblings are
// adjacent block IDs, dispatched together -> near-zero wait) -> G2 tile (mt,nt).
// Perfectly balanced (t1+t2 per block), HW pipelines 4.5 rounds across 256 CUs
// with ~3 blocks/CU co-resident (32KB LDS). Same-nt blocks all land on XCD nt%8
// -> B panels XCD-local. Deadlock-free: the oldest unfinished mt-group's G1s are
// all dispatched (window >> 16), so progress is monotone.
__global__ __launch_bounds__(256, 2) void gemm_fused(
    const u16* __restrict__ xb, const u16* __restrict__ W1b,
    const u16* __restrict__ W2b, u16* __restrict__ hbuf, u16* __restrict__ yt,
    int* __restrict__ meta) {
  __shared__ u16 lds[16384];   // 32KB: A 16K + B 16K
  const int tid = threadIdx.x;
  const int j = blockIdx.x;
  const int mt = j >> 4, nt = j & 15;
  const int slot0 = mt * 128;
  const int* toklist = meta + M_TOK;
  const int tot = meta[M_TOT];

  if (slot0 < tot) {
    int e = 0;
#pragma unroll
    for (int i = 1; i < NEXP; ++i) e += (slot0 >= meta[8 + i]);
    tile128<2048, true>(xb, W1b + (size_t)e * 2048 * 2048, hbuf, toklist, 0,
                        lds, slot0, nt, tid);
  }
  bump(&meta[M_DONE + mt], tid);
  if (slot0 >= tot) return;

  if (tid == 0) spin_ge(&meta[M_DONE + mt], 16);
  __syncthreads();

  int e = 0;
#pragma unroll
  for (int i = 1; i < NEXP; ++i) e += (slot0 >= meta[8 + i]);
  const int vend = meta[8 + e] + meta[e];
  tile128<1024, false>(hbuf, W2b + (size_t)e * 2048 * 1024, yt, toklist, vend,
                       lds, slot0, nt, tid);
}

// ---------------- combine (token-major yt: rows 2t, 2t+1) ----------------
__global__ void combine_k(const u16* __restrict__ yt, const float* __restrict__ ew,
                          float* __restrict__ out) {
  const int idx = blockIdx.x * 256 + threadIdx.x;
  const int t = idx >> 8;
  const int pos = (idx & 255) * 8;
  const float w0 = ew[t * 2];
  const float w1 = ew[t * 2 + 1];
  const u16x8 v0 = *(const u16x8*)(yt + (size_t)(t * 2) * HID + pos);
  const u16x8 v1 = *(const u16x8*)(yt + (size_t)(t * 2 + 1) * HID + pos);
  float* dst = out + (size_t)t * HID + pos;
  float4 o0, o1;
  o0.x = w0 * bf2f(v0[0]) + w1 * bf2f(v1[0]);
  o0.y = w0 * bf2f(v0[1]) + w1 * bf2f(v1[1]);
  o0.z = w0 * bf2f(v0[2]) + w1 * bf2f(v1[2]);
  o0.w = w0 * bf2f(v0[3]) + w1 * bf2f(v1[3]);
  o1.x = w0 * bf2f(v0[4]) + w1 * bf2f(v1[4]);
  o1.y = w0 * bf2f(v0[5]) + w1 * bf2f(v1[5]);
  o1.z = w0 * bf2f(v0[6]) + w1 * bf2f(v1[6]);
  o1.w = w0 * bf2f(v0[7]) + w1 * bf2f(v1[7]);
  *(float4*)dst = o0;
  *(float4*)(dst + 4) = o1;
}

// ---------------- launch ----------------
extern "C" void kernel_launch(void* const* d_in, const int* in_sizes, int n_in,
                              void* d_out, int out_size, void* d_ws, size_t ws_size,
                              hipStream_t stream) {
  const float* x    = (const float*)d_in[0];
  const int*   w1   = (const int*)d_in[1];
  const float* w1s  = (const float*)d_in[2];
  const int*   w2   = (const int*)d_in[3];
  const float* w2s  = (const float*)d_in[4];
  const float* ew   = (const float*)d_in[5];
  const int*   eidx = (const int*)d_in[6];
  float* out = (float*)d_out;

  char* ws = (char*)d_ws;
  const size_t OFF_W1B  = 0;           // 67,108,864
  const size_t OFF_W2B  = 67108864;    // 33,554,432
  const size_t OFF_XB   = 100663296;   // 16,777,216
  const size_t OFF_H    = 117440512;   // 9216*1024*2 = 18,874,368 (<= 20,971,520 slot)
  const size_t OFF_YT   = 138412032;   // 8192*2048*2 = 33,554,432 (token-major)
  const size_t OFF_META = 171966464;   // 9472 ints -> pad 76,800
  const size_t NEED     = 172043264;   // < 174,133,376 proven available (R1)
  if (ws_size < NEED) return;

  u16* W1b  = (u16*)(ws + OFF_W1B);
  u16* W2b  = (u16*)(ws + OFF_W2B);
  u16* xb   = (u16*)(ws + OFF_XB);
  u16* hbuf = (u16*)(ws + OFF_H);
  u16* yt   = (u16*)(ws + OFF_YT);
  int* meta = (int*)(ws + OFF_META);

  router_count<<<1, 256, 0, stream>>>(eidx, meta);
  init_k<<<SLOT_CAP / 256, 256, 0, stream>>>(meta);
  router_assign<<<T_TOK / 256, 256, 0, stream>>>(eidx, meta);

  prep_k<<<28672, 256, 0, stream>>>(w1, w1s, w2, w2s, x, W1b, W2b, xb);

  gemm_fused<<<NT_M * NT_N, 256, 0, stream>>>(xb, W1b, W2b, hbuf, yt, meta);

  combine_k<<<(T_TOK * HID) / (256 * 8), 256, 0, stream>>>(yt, ew, out);
}

// Round 14
// 254.301 us; speedup vs baseline: 1.2775x; 1.2775x over previous
//
#include <hip/hip_runtime.h>
#include <cstdint>
#include <cstddef>

typedef unsigned int u32;
typedef unsigned short u16;
typedef __bf16 bf16x8 __attribute__((ext_vector_type(8)));
typedef float f32x4 __attribute__((ext_vector_type(4)));
typedef u16 u16x8 __attribute__((ext_vector_type(8)));

static constexpr int T_TOK = 4096;
static constexpr int HID   = 2048;
static constexpr int INTER = 1024;
static constexpr int NEXP  = 8;
static constexpr int TOPK  = 2;
static constexpr int SLOT_CAP = 10240;   // 8192 real + per-expert 256-align pad
static constexpr int NT_M = 40;

// meta int indices
static constexpr int M_TOT    = 16;
static constexpr int M_CUR    = 17;    // 8 router cursors
static constexpr int M_DONE   = 40;    // 40 per-mt done counters
static constexpr int M_TOK    = 96;    // toklist[SLOT_CAP] (slot -> t*2+k)
static constexpr int M_SLOTOF = 96 + SLOT_CAP;  // slotof[T*K] (t*2+k -> slot)

__device__ __forceinline__ u16 f2bf(float f) {
  u32 u = __builtin_bit_cast(u32, f);
  u32 r = (u + 0x7fffu + ((u >> 16) & 1u)) >> 16;
  return (u16)r;
}
__device__ __forceinline__ float bf2f(u16 h) {
  return __builtin_bit_cast(float, (u32)h << 16);
}

// RELAXED poll + one acquire fence after success (R11-validated).
__device__ __forceinline__ void spin_ge(int* p, int target) {
  while (__hip_atomic_load(p, __ATOMIC_RELAXED, __HIP_MEMORY_SCOPE_AGENT) < target)
    __builtin_amdgcn_s_sleep(8);
  __builtin_amdgcn_fence(__ATOMIC_ACQUIRE, "agent");
}
// stores done -> __syncthreads() (drains all waves' vmcnt) -> tid0 release RMW.
__device__ __forceinline__ void bump(int* p, int tid) {
  __syncthreads();
  if (tid == 0)
    __hip_atomic_fetch_add(p, 1, __ATOMIC_RELEASE, __HIP_MEMORY_SCOPE_AGENT);
}

// ---------------- router ----------------
__global__ void router_count(const int* __restrict__ eidx, int* __restrict__ meta) {
  __shared__ int cnt[NEXP];
  const int tid = threadIdx.x;
  if (tid < NEXP) cnt[tid] = 0;
  __syncthreads();
  for (int i = tid; i < T_TOK * TOPK; i += 256) atomicAdd(&cnt[eidx[i]], 1);
  __syncthreads();
  if (tid == 0) {
    int off = 0;
    for (int e = 0; e < NEXP; ++e) {
      int c = cnt[e];
      meta[e] = c;
      meta[8 + e] = off;
      meta[M_CUR + e] = off;
      off += (c + 255) & ~255;      // 256-aligned regions (BM=256)
    }
    meta[M_TOT] = off;
  }
}

__global__ void init_k(int* __restrict__ meta) {
  const int i = blockIdx.x * 256 + threadIdx.x;
  if (i < SLOT_CAP) meta[M_TOK + i] = 0;   // pad slots gather token 0
  if (i >= 25 && i < 80) meta[i] = 0;      // DONE[40] etc.
}

__global__ void router_assign(const int* __restrict__ eidx, int* __restrict__ meta) {
  const int t = blockIdx.x * 256 + threadIdx.x;
  if (t >= T_TOK) return;
  int* cursors = meta + M_CUR;
  int* toklist = meta + M_TOK;
  int* slotof  = meta + M_SLOTOF;
  for (int k = 0; k < TOPK; ++k) {
    const int e = eidx[t * TOPK + k];
    const int pos = atomicAdd(&cursors[e], 1);
    toklist[pos] = t * 2 + k;
    slotof[t * 2 + k] = pos;
  }
}

// ---------------- dequant helper (1 thread = 4 int32 -> 8 bf16) ----------------
template <int CPR>
__device__ __forceinline__ void deq1(const int* __restrict__ p, const float* __restrict__ s,
                                     u16* __restrict__ w, int gid) {
  const int row = gid / CPR;
  const int cid = gid % CPR;
  const int4 pk = *(const int4*)(p + (size_t)gid * 4);
  const float sc = s[(size_t)row * (CPR / 4) + (cid >> 2)];
  int v[4] = {pk.x, pk.y, pk.z, pk.w};
  u16x8 o;
#pragma unroll
  for (int b = 0; b < 4; ++b) {
    o[2 * b]     = f2bf((float)((v[b] & 15) - 8) * sc);
    o[2 * b + 1] = f2bf((float)(((v[b] >> 4) & 15) - 8) * sc);
  }
  *(u16x8*)(w + (size_t)gid * 8) = o;
}

// ------- merged prep: [0,16384) deqW1, [16384,24576) deqW2, [24576,34816) x-gather -------
// x-gather: one block per slot; xs[slot] = bf16(x[toklist[slot]>>1]). Runs after
// router_assign (same-stream order). Pad slots copy token 0 (valid, never combined).
__global__ void prep_k(const int* __restrict__ w1, const float* __restrict__ w1s,
                       const int* __restrict__ w2, const float* __restrict__ w2s,
                       const float* __restrict__ x, u16* __restrict__ W1b,
                       u16* __restrict__ W2b, u16* __restrict__ xs,
                       const int* __restrict__ meta) {
  const int blk = blockIdx.x;
  if (blk < 16384) {
    deq1<256>(w1, w1s, W1b, blk * 256 + threadIdx.x);
  } else if (blk < 24576) {
    deq1<128>(w2, w2s, W2b, (blk - 16384) * 256 + threadIdx.x);
  } else {
    const int slot = blk - 24576;
    const int tok = meta[M_TOK + slot] >> 1;
    const float* src = x + (size_t)tok * HID + threadIdx.x * 8;
    const float4 a = *(const float4*)src;
    const float4 b = *(const float4*)(src + 4);
    u16x8 o;
    o[0] = f2bf(a.x); o[1] = f2bf(a.y); o[2] = f2bf(a.z); o[3] = f2bf(a.w);
    o[4] = f2bf(b.x); o[5] = f2bf(b.y); o[6] = f2bf(b.z); o[7] = f2bf(b.w);
    *(u16x8*)(xs + (size_t)slot * HID + threadIdx.x * 8) = o;
  }
}

// ---------------- 256x256 GEMM tile body (R11 2-phase, conflict-free swizzle) ----------------
// C[slot, n] = sum_k A[slot0+r, k] * B[n, k]  (B K-major; A now slot-contiguous —
// pre-gathered xs for G1, hbuf for G2). BM=BN=256, BK=64, 8 waves (2M x 4N),
// wave tile 128x64, dbuf LDS 2x64KB. Swizzle o^=((o>>7)&3)<<4 (PMC-verified 0
// conflicts). G1M: fused silu(gate)*up epilogue into hbuf[slot].
// !G1M: slot-major contiguous writes into ys (aliases xs: rows of mt are dead
// once done[mt]==8, which gates G2).
template <int KT, bool G1M>
__device__ void gemm_body(const u16* __restrict__ A, const u16* __restrict__ Be,
                          u16* __restrict__ Cout, u16* lds, int slot0, int nt, int tid) {
  static constexpr int NT = KT / 64;
  char* ldsB = (char*)lds;

  const u16* asrc[4];
  const u16* bsrc[4];
#pragma unroll
  for (int j = 0; j < 4; ++j) {
    const int L = j * 8192 + tid * 16;
    const int S = L >> 10;
    int o = L & 1023;
    o ^= ((o >> 7) & 3) << 4;
    const int r = (S >> 1) * 16 + (o >> 6);
    const int cb = (S & 1) * 64 + (o & 63);
    asrc[j] = A + (size_t)(slot0 + r) * KT + (cb >> 1);
    int brow;
    if (G1M) {
      const int g = r >> 6, j6 = r & 63;
      brow = nt * 128 + g * 32 + (j6 & 31) + ((j6 >> 5) << 10);  // gate | up+1024
    } else {
      brow = nt * 256 + r;
    }
    bsrc[j] = Be + (size_t)brow * KT + (cb >> 1);
  }

#define STAGE(kt_, c_)                                                                \
  do {                                                                                \
    char* dA_ = ldsB + (c_) * 65536;                                                  \
    char* dB_ = dA_ + 32768;                                                          \
    _Pragma("unroll") for (int j = 0; j < 4; ++j)                                     \
        __builtin_amdgcn_global_load_lds(                                             \
            (const __attribute__((address_space(1))) void*)(asrc[j] + (kt_) * 64),    \
            (__attribute__((address_space(3))) void*)(dA_ + j * 8192 + tid * 16),     \
            16, 0, 0);                                                                \
    _Pragma("unroll") for (int j = 0; j < 4; ++j)                                     \
        __builtin_amdgcn_global_load_lds(                                             \
            (const __attribute__((address_space(1))) void*)(bsrc[j] + (kt_) * 64),    \
            (__attribute__((address_space(3))) void*)(dB_ + j * 8192 + tid * 16),     \
            16, 0, 0);                                                                \
  } while (0)

  const int lane = tid & 63;
  const int wid = tid >> 6;
  const int wm = (wid >> 2) * 128;
  const int wn = (wid & 3) * 64;
  const int fr = lane & 15;
  const int qq = lane >> 4;
  const int swz = (qq * 16) ^ (((fr >> 1) & 3) << 4);

  const int abase = (wm >> 4) * 2048 + fr * 64 + swz;
  const int bbase = 32768 + (wn >> 4) * 2048 + fr * 64 + swz;

  f32x4 acc[8][4];
#pragma unroll
  for (int m = 0; m < 8; ++m)
#pragma unroll
    for (int n = 0; n < 4; ++n) acc[m][n] = (f32x4)0.0f;

#define COMPUTE(c_)                                                                   \
  do {                                                                                \
    const char* bb_ = ldsB + (c_) * 65536;                                            \
    bf16x8 bfr_[4][2];                                                                \
    _Pragma("unroll") for (int nf = 0; nf < 4; ++nf)                                  \
        _Pragma("unroll") for (int ks = 0; ks < 2; ++ks)                              \
            bfr_[nf][ks] = *(const bf16x8*)(bb_ + bbase + nf * 2048 + ks * 1024);     \
    _Pragma("unroll") for (int mh = 0; mh < 2; ++mh) {                                \
      bf16x8 af_[4][2];                                                               \
      _Pragma("unroll") for (int mf = 0; mf < 4; ++mf)                                \
          _Pragma("unroll") for (int ks = 0; ks < 2; ++ks)                            \
              af_[mf][ks] = *(const bf16x8*)(bb_ + abase + mh * 8192 + mf * 2048 +    \
                                             ks * 1024);                              \
      __builtin_amdgcn_s_setprio(1);                                                  \
      _Pragma("unroll") for (int mf = 0; mf < 4; ++mf)                                \
          _Pragma("unroll") for (int nf = 0; nf < 4; ++nf)                            \
              _Pragma("unroll") for (int ks = 0; ks < 2; ++ks)                        \
                  acc[mh * 4 + mf][nf] = __builtin_amdgcn_mfma_f32_16x16x32_bf16(     \
                      af_[mf][ks], bfr_[nf][ks], acc[mh * 4 + mf][nf], 0, 0, 0);      \
      __builtin_amdgcn_s_setprio(0);                                                  \
    }                                                                                 \
  } while (0)

  STAGE(0, 0);
#pragma unroll 1
  for (int kt = 0; kt < NT; kt += 2) {
    asm volatile("s_waitcnt vmcnt(0)" ::: "memory");
    __builtin_amdgcn_s_barrier();
    __builtin_amdgcn_sched_barrier(0);
    if (kt + 1 < NT) STAGE(kt + 1, 1);
    COMPUTE(0);
    asm volatile("s_waitcnt vmcnt(0)" ::: "memory");
    __builtin_amdgcn_s_barrier();
    __builtin_amdgcn_sched_barrier(0);
    if (kt + 2 < NT) STAGE(kt + 2, 0);
    COMPUTE(1);
  }
#undef STAGE
#undef COMPUTE

  // epilogue: C/D layout col=lane&15, row=(lane>>4)*4+j  [m89-verified]
  if (G1M) {
    const int g = wid & 3;
#pragma unroll
    for (int mi = 0; mi < 8; ++mi)
#pragma unroll
      for (int n = 0; n < 2; ++n)
#pragma unroll
        for (int jj = 0; jj < 4; ++jj) {
          const float gv = acc[mi][n][jj];
          const float uv = acc[mi][n + 2][jj];
          const float hv = gv / (1.0f + __expf(-gv)) * uv;
          const int row = slot0 + wm + mi * 16 + qq * 4 + jj;
          Cout[(size_t)row * INTER + nt * 128 + g * 32 + n * 16 + fr] = f2bf(hv);
        }
  } else {
    // slot-major contiguous writes (ys aliases xs; mt's rows dead by gating)
#pragma unroll
    for (int mi = 0; mi < 8; ++mi)
#pragma unroll
      for (int jj = 0; jj < 4; ++jj) {
        const int row = slot0 + wm + mi * 16 + qq * 4 + jj;
        const int col = nt * 256 + wn + fr;
#pragma unroll
        for (int n = 0; n < 4; ++n)
          Cout[(size_t)row * HID + col + n * 16] = f2bf(acc[mi][n][jj]);
      }
  }
}

// ---------------- static-schedule tile runners ----------------
__device__ __forceinline__ void run_g1(const u16* xs, const u16* W1b, u16* hbuf,
                                       int* meta, u16* lds, int mt, int nt, int tid) {
  const int slot0 = mt * 256;
  if (slot0 < meta[M_TOT]) {
    int e = 0;
#pragma unroll
    for (int i = 1; i < NEXP; ++i) e += (slot0 >= meta[8 + i]);
    gemm_body<2048, true>(xs, W1b + (size_t)e * 2048 * 2048, hbuf, lds, slot0, nt, tid);
  }
  bump(&meta[M_DONE + mt], tid);   // bump even when skipped so spins reach 8
}

__device__ __forceinline__ void run_g2(const u16* hbuf, const u16* W2b, u16* ys,
                                       int* meta, u16* lds, int mt, int nt, int tid) {
  const int slot0 = mt * 256;
  if (slot0 >= meta[M_TOT]) return;
  int e = 0;
#pragma unroll
  for (int i = 1; i < NEXP; ++i) e += (slot0 >= meta[8 + i]);
  if (tid == 0) spin_ge(&meta[M_DONE + mt], 8);
  __syncthreads();
  gemm_body<1024, false>(hbuf, W2b + (size_t)e * 2048 * 1024, ys, lds, slot0, nt, tid);
}

// ---------------- static overlapped GEMM kernel (256 blocks, R11 schedule) ----------------
// G1 round 1: block b -> (mt=b%32, nt=b/32); same-mt blocks on XCD mt%8 (A/xs local).
// G1 round 2: blocks 0..63 -> (mt=32+b%8, nt=b/8).
// G2: blocks 64..255 take the 256 tiles of mts 0..31 (mt%8==b%8 keeps hbuf
//     L2-local); blocks 0..63 take G2 of mts 32..39 after their own G1.
__global__ __launch_bounds__(512, 2) void gemm_static(
    const u16* __restrict__ xs, const u16* __restrict__ W1b,
    const u16* __restrict__ W2b, u16* __restrict__ hbuf, u16* __restrict__ ys,
    int* __restrict__ meta) {
  __shared__ u16 lds[2 * 32768];
  const int tid = threadIdx.x;
  const int b = blockIdx.x;

  run_g1(xs, W1b, hbuf, meta, lds, b & 31, b >> 5, tid);
  if (b < 64) {
    run_g1(xs, W1b, hbuf, meta, lds, 32 + (b & 7), b >> 3, tid);
    run_g2(hbuf, W2b, ys, meta, lds, 32 + (b & 7), b >> 3, tid);
  } else {
    const int x = b & 7, q = (b - 64) >> 3;   // q in 0..23
    {
      const int k = q;
      run_g2(hbuf, W2b, ys, meta, lds, x + 8 * (k & 3), k >> 2, tid);
    }
    if (q < 8) {
      const int k = q + 24;
      run_g2(hbuf, W2b, ys, meta, lds, x + 8 * (k & 3), k >> 2, tid);
    }
  }
}

// ---------------- combine (slot-major ys via slotof) ----------------
__global__ void combine_k(const u16* __restrict__ ys, const float* __restrict__ ew,
                          const int* __restrict__ meta, float* __restrict__ out) {
  const int idx = blockIdx.x * 256 + threadIdx.x;
  const int t = idx >> 8;
  const int pos = (idx & 255) * 8;
  const int* slotof = meta + M_SLOTOF;
  const int s0 = slotof[t * 2];
  const int s1 = slotof[t * 2 + 1];
  const float w0 = ew[t * 2];
  const float w1 = ew[t * 2 + 1];
  const u16x8 v0 = *(const u16x8*)(ys + (size_t)s0 * HID + pos);
  const u16x8 v1 = *(const u16x8*)(ys + (size_t)s1 * HID + pos);
  float* dst = out + (size_t)t * HID + pos;
  float4 o0, o1;
  o0.x = w0 * bf2f(v0[0]) + w1 * bf2f(v1[0]);
  o0.y = w0 * bf2f(v0[1]) + w1 * bf2f(v1[1]);
  o0.z = w0 * bf2f(v0[2]) + w1 * bf2f(v1[2]);
  o0.w = w0 * bf2f(v0[3]) + w1 * bf2f(v1[3]);
  o1.x = w0 * bf2f(v0[4]) + w1 * bf2f(v1[4]);
  o1.y = w0 * bf2f(v0[5]) + w1 * bf2f(v1[5]);
  o1.z = w0 * bf2f(v0[6]) + w1 * bf2f(v1[6]);
  o1.w = w0 * bf2f(v0[7]) + w1 * bf2f(v1[7]);
  *(float4*)dst = o0;
  *(float4*)(dst + 4) = o1;
}

// ---------------- launch ----------------
extern "C" void kernel_launch(void* const* d_in, const int* in_sizes, int n_in,
                              void* d_out, int out_size, void* d_ws, size_t ws_size,
                              hipStream_t stream) {
  const float* x    = (const float*)d_in[0];
  const int*   w1   = (const int*)d_in[1];
  const float* w1s  = (const float*)d_in[2];
  const int*   w2   = (const int*)d_in[3];
  const float* w2s  = (const float*)d_in[4];
  const float* ew   = (const float*)d_in[5];
  const int*   eidx = (const int*)d_in[6];
  float* out = (float*)d_out;

  char* ws = (char*)d_ws;
  const size_t OFF_W1B  = 0;           // 67,108,864
  const size_t OFF_W2B  = 67108864;    // 33,554,432
  const size_t OFF_XS   = 100663296;   // 10240*2048*2 = 41,943,040 (xs; ys aliases)
  const size_t OFF_H    = 142606336;   // 10240*1024*2 = 20,971,520
  const size_t OFF_META = 163577856;   // ~26.9K ints -> pad 131,072
  const size_t NEED     = 163708928;   // < 172,043,264 proven available (R9)
  if (ws_size < NEED) return;

  u16* W1b  = (u16*)(ws + OFF_W1B);
  u16* W2b  = (u16*)(ws + OFF_W2B);
  u16* xs   = (u16*)(ws + OFF_XS);     // slot-gathered activations; G2 output aliases
  u16* hbuf = (u16*)(ws + OFF_H);
  int* meta = (int*)(ws + OFF_META);

  router_count<<<1, 256, 0, stream>>>(eidx, meta);
  init_k<<<SLOT_CAP / 256, 256, 0, stream>>>(meta);
  router_assign<<<T_TOK / 256, 256, 0, stream>>>(eidx, meta);

  // prep after router (x-gather needs toklist); 16384 + 8192 + 10240 blocks
  prep_k<<<34816, 256, 0, stream>>>(w1, w1s, w2, w2s, x, W1b, W2b, xs, meta);

  gemm_static<<<256, 512, 0, stream>>>(xs, W1b, W2b, hbuf, xs, meta);

  combine_k<<<(T_TOK * HID) / (256 * 8), 256, 0, stream>>>(xs, ew, meta, out);
}